// Round 18
// baseline (284.031 us; speedup 1.0000x reference)
//
#include <hip/hip_runtime.h>
#include <hip/hip_bf16.h>
#include <math.h>

#define D_   4096
#define NIMG 16
#define NPER 64
#define RPER 512
#define NTOT 1024
#define RTOT 8192
#define DC   2048
#define DT   1024
#define LDW  8192    // wswo_bf row stride (4096 ws | 4096 wo), bf16

typedef __attribute__((ext_vector_type(4))) float f32x4;
typedef __attribute__((ext_vector_type(8))) short bf16x8;

#define GLD16(gp, lp) __builtin_amdgcn_global_load_lds( \
    (const __attribute__((address_space(1))) unsigned int*)(gp), \
    (__attribute__((address_space(3))) unsigned int*)(lp), 16, 0, 0)

template<int N> __device__ __forceinline__ void waitvm() {
    asm volatile("s_waitcnt vmcnt(%0)" :: "n"(N) : "memory");
}

__device__ __forceinline__ void fma4(float4& d, float s, const float4 c) {
    d.x = fmaf(s, c.x, d.x); d.y = fmaf(s, c.y, d.y);
    d.z = fmaf(s, c.z, d.z); d.w = fmaf(s, c.w, d.w);
}
__device__ __forceinline__ void st4bf(__hip_bfloat16* p, float4 v) {
    union { __hip_bfloat16 h[4]; ushort4 u; } cv;
    cv.h[0] = __float2bfloat16(v.x); cv.h[1] = __float2bfloat16(v.y);
    cv.h[2] = __float2bfloat16(v.z); cv.h[3] = __float2bfloat16(v.w);
    *(ushort4*)p = cv.u;
}
__device__ __forceinline__ float bf2f(ushort u) {
    union { float f; unsigned int i; } c; c.i = (unsigned int)u << 16; return c.f;
}
__device__ __forceinline__ ushort f2bfu(float v) {
    union { __hip_bfloat16 h; ushort u; } c; c.h = __float2bfloat16(v); return c.u;
}

// ---------------------------------------------------------------------------
// ONE up-front dispatch: cast obj/Ws/Wo/Wc/Wt1(rearranged)/Wt2 -> bf16,
// concat biases. Sources are read-once -> non-temporal loads.
// wt1r[r][c] = Wt1[r&1023][(r>>10)*2048 + c]
// ---------------------------------------------------------------------------
__global__ __launch_bounds__(256) void cast_all(
    const float* __restrict__ obj, __hip_bfloat16* __restrict__ obj_bf,
    const float* __restrict__ Ws, const float* __restrict__ Wo,
    const float* __restrict__ Wc, __hip_bfloat16* __restrict__ wbuf,
    const float* __restrict__ Wt1, __hip_bfloat16* __restrict__ wt1r,
    const float* __restrict__ Wt2, __hip_bfloat16* __restrict__ wt2b,
    const float* __restrict__ b0, const float* __restrict__ b1,
    const float* __restrict__ b2, float* __restrict__ cb)
{
    const int b = blockIdx.x;
    const int t = threadIdx.x;
    if (b >= 26624) {                                    // bias concat
        const int i = (b - 26624) * 256 + t;             // 0..10239
        float v;
        if (i < 4096) v = b0[i];
        else if (i < 8192) v = b1[i - 4096];
        else v = b2[i - 8192];
        cb[i] = v;
        return;
    }
    const float* s; __hip_bfloat16* d;
    if (b < 2048)       { s = obj + (size_t)b * 2048;            d = obj_bf + (size_t)b * 2048; }
    else if (b < 10240) { const int rb = b - 2048;  s = Ws + (size_t)rb * 2048; d = wbuf + (size_t)rb * 2048; }
    else if (b < 18432) { const int rb = b - 10240; s = Wo + (size_t)rb * 2048; d = wbuf + 16777216 + (size_t)rb * 2048; }
    else if (b < 22528) { const int rb = b - 18432; s = Wc + (size_t)rb * 2048; d = wbuf + 33554432 + (size_t)rb * 2048; }
    else if (b < 24576) { const int r = b - 22528;                // wt1 rearranged
                          s = Wt1 + (size_t)(r & 1023) * 4096 + (r >> 10) * 2048;
                          d = wt1r + (size_t)r * 2048; }
    else                { const int rb = b - 24576; s = Wt2 + (size_t)rb * 2048; d = wt2b + (size_t)rb * 2048; }
    const int i = t * 8;
    f32x4 v0 = __builtin_nontemporal_load((const f32x4*)(s + i));
    f32x4 v1 = __builtin_nontemporal_load((const f32x4*)(s + i + 4));
    union { __hip_bfloat16 h[8]; ushort4 u[2]; } cv;
    cv.h[0] = __float2bfloat16(v0[0]); cv.h[1] = __float2bfloat16(v0[1]);
    cv.h[2] = __float2bfloat16(v0[2]); cv.h[3] = __float2bfloat16(v0[3]);
    cv.h[4] = __float2bfloat16(v1[0]); cv.h[5] = __float2bfloat16(v1[1]);
    cv.h[6] = __float2bfloat16(v1[2]); cv.h[7] = __float2bfloat16(v1[3]);
    *(ushort4*)(d + i)     = cv.u[0];
    *(ushort4*)(d + i + 4) = cv.u[1];
}

// ---------------------------------------------------------------------------
// Fused GEMM (ws|wo|conv) v6 — LDS-traffic-minimizing wave geometry.
// 256x256 tile, 256 thr = 4 waves (2M x 2N), wave tile 128x128, BK=32.
// Rationale: v4/v5 (8 waves, 128x64 wave tile) issue 96 ds_read_b128/tile
// (96 KB LDS traffic, ~1150 cyc @85 B/cyc) -> LDS-read-bound. 4 waves at
// 128x128 read 64 (8A+8B each) = 64 KB/tile (-33%), MFMA:ds 2.67->4.0.
// Schedule = v4's proven minimal-sync: 3 LDS buffers, 2-tiles-ahead
// staging (8 gld/thread/tile), counted vmcnt(8) + ONE s_barrier per tile.
// acc 8x8 f32x4 = 256 VGPR + frags ~70: under 512 no-spill; 1 wave/SIMD.
// Swizzle: phys 16B slot p of row r holds K-quarter p ^ ((r>>1)&3).
// Epilogue: per-wave LDS-bounce (4 passes of 64x64) -> 16B bf16 stores.
// ---------------------------------------------------------------------------
__global__ __launch_bounds__(256, 1) void gemm8v6(
    const ushort* __restrict__ A, const ushort* __restrict__ B,
    const float* __restrict__ bias,
    __hip_bfloat16* __restrict__ C2, __hip_bfloat16* __restrict__ C3,
    int M, int K)
{
    __shared__ ushort sh[3][16384];   // per buf: A 8192 ushorts | B 8192

    const int t = threadIdx.x;
    const int lane = t & 63;
    const int wid = t >> 6;           // 4 waves
    const int wm = wid >> 1, wn = wid & 1;

    const int MT = M >> 8;                                // 4
    const int G = gridDim.x;                              // 160 (G%8==0)
    const int wgid = (blockIdx.x & 7) * (G >> 3) + (blockIdx.x >> 3);
    const int nt = wgid / MT, mt = wgid % MT;
    const int bm = mt * 256, bn = nt * 256;

    // --- staging: thread serves 8 slots {t + i*256}; 0..1023 A, 1024..2047 B
    const ushort* gp[8];
    int loff[8];
#pragma unroll
    for (int i = 0; i < 8; ++i) {
        const int slot = i * 256 + t;
        const bool isA = slot < 1024;
        const int s2 = isA ? slot : slot - 1024;
        const int row = s2 >> 2;
        const int q = (s2 & 3) ^ ((row >> 1) & 3);        // pre-swizzled source
        gp[i] = (isA ? A + (size_t)(bm + row) * K : B + (size_t)(bn + row) * K) + q * 8;
        loff[i] = slot * 8;                               // linear LDS dest
    }

    // --- fragment read offsets (ushort units; row pitch 32) ---
    const int sx = ((lane >> 4) ^ ((lane >> 1) & 3)) * 8;
    int aoff[8], boff[8];
#pragma unroll
    for (int m = 0; m < 8; ++m)
        aoff[m] = (wm * 128 + m * 16 + (lane & 15)) * 32 + sx;
#pragma unroll
    for (int n = 0; n < 8; ++n)
        boff[n] = 8192 + (wn * 128 + n * 16 + (lane & 15)) * 32 + sx;

    f32x4 acc[8][8] = {};
    const int NT = K >> 5;   // 128

    // prologue: stage tiles 0 and 1
#pragma unroll
    for (int i = 0; i < 8; ++i) GLD16(gp[i], &sh[0][loff[i]]);
#pragma unroll
    for (int i = 0; i < 8; ++i) GLD16(gp[i] + 32, &sh[1][loff[i]]);
    waitvm<8>();                      // tile 0 resident; tile 1 in flight
    __builtin_amdgcn_sched_barrier(0);
    __builtin_amdgcn_s_barrier();
    __builtin_amdgcn_sched_barrier(0);

    for (int T = 0; T < NT; ++T) {
        const ushort* lb = sh[T % 3];
        ushort* nb = sh[(T + 2) % 3];
        const bool pf = (T + 2 < NT);
        const int kpos = (T + 2) << 5;

        if (pf) {
#pragma unroll
            for (int i = 0; i < 8; ++i) GLD16(gp[i] + kpos, nb + loff[i]);
        }

        bf16x8 bv[8], af[8];
#pragma unroll
        for (int n = 0; n < 8; ++n) bv[n] = *(const bf16x8*)(lb + boff[n]);
#pragma unroll
        for (int m = 0; m < 8; ++m) af[m] = *(const bf16x8*)(lb + aoff[m]);
        __builtin_amdgcn_s_setprio(1);
#pragma unroll
        for (int m = 0; m < 8; ++m)
#pragma unroll
            for (int n = 0; n < 8; ++n)
                acc[m][n] = __builtin_amdgcn_mfma_f32_16x16x32_bf16(
                    af[m], bv[n], acc[m][n], 0, 0, 0);
        __builtin_amdgcn_s_setprio(0);

        __builtin_amdgcn_sched_barrier(0);
        if (pf) waitvm<8>(); else waitvm<0>();   // tile T+1 resident
        __builtin_amdgcn_sched_barrier(0);
        __builtin_amdgcn_s_barrier();
        __builtin_amdgcn_sched_barrier(0);
    }

    // --- epilogue: LDS-bounce, wave-private patch 64x64 (pitch 72), 4 passes
    ushort* patch = ((ushort*)sh) + wid * (64 * 72);
    const bool doRelu = (bn >= 8192);
    const int lcol8 = (lane & 7) * 8;
#pragma unroll
    for (int rc = 0; rc < 2; ++rc) {
#pragma unroll
        for (int cc = 0; cc < 2; ++cc) {
#pragma unroll
            for (int m2 = 0; m2 < 4; ++m2) {
#pragma unroll
                for (int n2 = 0; n2 < 4; ++n2) {
                    const int m = rc * 4 + m2, n = cc * 4 + n2;
                    const float bz = bias[bn + wn * 128 + cc * 64 + n2 * 16 + (lane & 15)];
#pragma unroll
                    for (int rg = 0; rg < 4; ++rg) {
                        float v = acc[m][n][rg] + bz;
                        if (doRelu) v = fmaxf(v, 0.f);
                        const int lr = m2 * 16 + ((lane >> 4) << 2) + rg;
                        const int lc = n2 * 16 + (lane & 15);
                        patch[lr * 72 + lc] = f2bfu(v);
                    }
                }
            }
#pragma unroll
            for (int m2 = 0; m2 < 4; ++m2) {
#pragma unroll
                for (int pass = 0; pass < 2; ++pass) {
                    const int lr = m2 * 16 + pass * 8 + (lane >> 3);
                    uint4 v4 = *(const uint4*)(patch + lr * 72 + lcol8);
                    const int grow = bm + wm * 128 + rc * 64 + lr;
                    const int gcol = bn + wn * 128 + cc * 64 + lcol8;
                    if (gcol < 8192)
                        *(uint4*)((ushort*)C2 + (size_t)grow * LDW + gcol) = v4;
                    else
                        *(uint4*)((ushort*)C3 + (size_t)grow * 2048 + (gcol - 8192)) = v4;
                }
            }
        }
    }
}

// ---------------------------------------------------------------------------
// MFMA GEMM (round-4 schedule + r9 swizzle) — used for P-GEMM and wt2.
// mode: 0 = +bias (nullable), f32 out; 2 = relu(resid + . + bias), f32 out
// ---------------------------------------------------------------------------
template<int BM, int BN>
__global__ __launch_bounds__(256) void gemm_p2(
    const ushort* __restrict__ A, const ushort* __restrict__ B,
    const float* __restrict__ bias, const float* __restrict__ resid,
    float* __restrict__ C, int M, int K, int ldc, int mode)
{
    constexpr int MREP = BM / 32;
    constexpr int NREP = BN / 32;
    constexpr int SLOTS = (BM + BN) * 4;
    constexpr int NPW = SLOTS / 256;
    constexpr int BUFE = SLOTS * 8;

    __shared__ ushort lds[3][BUFE];

    const int t = threadIdx.x;
    const int lane = t & 63;
    const int wid = t >> 6;
    const int wr = wid >> 1, wc = wid & 1;

    const int MT = M / BM;
    const int G = gridDim.x;
    const int bid = blockIdx.x;
    const int wgid = (bid & 7) * (G >> 3) + (bid >> 3);
    const int nt = wgid / MT, mt = wgid % MT;
    const int bm = mt * BM, bn = nt * BN;

    const ushort* gp[NPW];
    int loff[NPW];
#pragma unroll
    for (int i = 0; i < NPW; ++i) {
        const int slot = i * 256 + t;
        const bool isA = slot < BM * 4;
        const int s2 = isA ? slot : slot - BM * 4;
        const int row = s2 >> 2;
        const int q = (s2 & 3) ^ ((row >> 1) & 3);
        gp[i] = (isA ? A + (size_t)(bm + row) * K : B + (size_t)(bn + row) * K) + q * 8;
        loff[i] = slot * 8;
    }

    auto stage = [&](int b, int kpos) {
#pragma unroll
        for (int i = 0; i < NPW; ++i) GLD16(gp[i] + kpos, &lds[b][loff[i]]);
    };

    int aoff[MREP], boff[NREP];
    const int sx = (((lane >> 4) ^ ((lane >> 1) & 3))) << 3;
#pragma unroll
    for (int m = 0; m < MREP; ++m)
        aoff[m] = (wr * (BM / 2) + (lane & 15) + m * 16) * 32 + sx;
#pragma unroll
    for (int n = 0; n < NREP; ++n)
        boff[n] = BM * 32 + (wc * (BN / 2) + (lane & 15) + n * 16) * 32 + sx;

    f32x4 acc[MREP][NREP] = {};

    const int NT = K >> 5;
    stage(0, 0);
    stage(1, 32);
    if constexpr (NPW == 2) waitvm<2>();
    else if constexpr (NPW == 3) waitvm<3>();
    else waitvm<4>();
    __builtin_amdgcn_sched_barrier(0);
    __builtin_amdgcn_s_barrier();
    __builtin_amdgcn_sched_barrier(0);

    for (int tt = 0; tt < NT; ++tt) {
        const bool pf = (tt + 2 < NT);
        if (pf) stage((tt + 2) % 3, (tt + 2) << 5);
        __builtin_amdgcn_sched_barrier(0);

        const ushort* lb = lds[tt % 3];
        bf16x8 af[MREP], bfv[NREP];
#pragma unroll
        for (int m = 0; m < MREP; ++m) af[m] = *(const bf16x8*)(lb + aoff[m]);
#pragma unroll
        for (int n = 0; n < NREP; ++n) bfv[n] = *(const bf16x8*)(lb + boff[n]);
#pragma unroll
        for (int m = 0; m < MREP; ++m)
#pragma unroll
            for (int n = 0; n < NREP; ++n)
                acc[m][n] = __builtin_amdgcn_mfma_f32_16x16x32_bf16(
                    af[m], bfv[n], acc[m][n], 0, 0, 0);

        __builtin_amdgcn_sched_barrier(0);
        if (pf) {
            if constexpr (NPW == 2) waitvm<2>();
            else if constexpr (NPW == 3) waitvm<3>();
            else waitvm<4>();
        } else {
            waitvm<0>();
        }
        __builtin_amdgcn_sched_barrier(0);
        __builtin_amdgcn_s_barrier();
        __builtin_amdgcn_sched_barrier(0);
    }

    const int col0 = bn + wc * (BN / 2) + (lane & 15);
    const int row0 = bm + wr * (BM / 2) + ((lane >> 4) << 2);
#pragma unroll
    for (int m = 0; m < MREP; ++m) {
#pragma unroll
        for (int n = 0; n < NREP; ++n) {
            const int cn = col0 + n * 16;
            const float bz = bias ? bias[cn] : 0.f;
#pragma unroll
            for (int rg = 0; rg < 4; ++rg) {
                const int gm = row0 + m * 16 + rg;
                float v = acc[m][n][rg] + bz;
                if (mode == 2)
                    v = fmaxf(v + resid[(size_t)gm * ldc + cn], 0.f);
                C[(size_t)gm * ldc + cn] = v;
            }
        }
    }
}

// ---------------------------------------------------------------------------
// atten[r] = sum_d ws[s[r],d] * wo[o[r],d] * phr[r,d] * Www[d]  + Wwb
// ws/wo bf16 in wswo (row stride LDW). XCD-grouped per image.
// ---------------------------------------------------------------------------
__global__ __launch_bounds__(256) void atten_kernel(
    const ushort* __restrict__ wswo, const float* __restrict__ phr,
    const int* __restrict__ rel, const float* __restrict__ Www,
    const float* __restrict__ Wwb, float* __restrict__ atten)
{
    const int r = (blockIdx.x & 7) * 1024 + (blockIdx.x >> 3);
    const int s = rel[r * 3 + 1], o = rel[r * 3 + 2];
    const int t = threadIdx.x;
    const ushort* pws = wswo + (size_t)s * LDW;
    const ushort* pwo = wswo + (size_t)o * LDW + 4096;
    const float*  pph = phr + (size_t)r * D_;
    float sum = 0.f;
#pragma unroll
    for (int half = 0; half < 2; ++half) {
        const int q = t * 8 + half * 2048;
        ushort4 w0 = *(const ushort4*)(pws + q);
        ushort4 w1 = *(const ushort4*)(pws + q + 4);
        ushort4 u0 = *(const ushort4*)(pwo + q);
        ushort4 u1 = *(const ushort4*)(pwo + q + 4);
        float4 p0 = *(const float4*)(pph + q);
        float4 p1 = *(const float4*)(pph + q + 4);
        float4 g0 = *(const float4*)(Www + q);
        float4 g1 = *(const float4*)(Www + q + 4);
        sum += bf2f(w0.x) * bf2f(u0.x) * p0.x * g0.x
             + bf2f(w0.y) * bf2f(u0.y) * p0.y * g0.y
             + bf2f(w0.z) * bf2f(u0.z) * p0.z * g0.z
             + bf2f(w0.w) * bf2f(u0.w) * p0.w * g0.w
             + bf2f(w1.x) * bf2f(u1.x) * p1.x * g1.x
             + bf2f(w1.y) * bf2f(u1.y) * p1.y * g1.y
             + bf2f(w1.z) * bf2f(u1.z) * p1.z * g1.z
             + bf2f(w1.w) * bf2f(u1.w) * p1.w * g1.w;
    }
    for (int off = 32; off > 0; off >>= 1) sum += __shfl_down(sum, off);
    __shared__ float red[4];
    if ((t & 63) == 0) red[t >> 6] = sum;
    __syncthreads();
    if (t == 0) atten[r] = red[0] + red[1] + red[2] + red[3] + Wwb[0];
}

// ---------------------------------------------------------------------------
__global__ __launch_bounds__(256) void build_A(
    const int* __restrict__ rel, const float* __restrict__ atten,
    float* __restrict__ Anorm)
{
    const int g = blockIdx.x;
    const int t = threadIdx.x;
    __shared__ float Am[64][64];
    __shared__ float S[64];
    __shared__ int headSh;
    for (int i = t; i < 4096; i += 256) ((float*)Am)[i] = 0.f;
    if (t == 0) headSh = 0x7fffffff;

    int lmin = 0x7fffffff;
    for (int rr = t; rr < RPER; rr += 256) {
        const int base = (g * RPER + rr) * 3;
        lmin = min(lmin, min(rel[base + 1], rel[base + 2]));
    }
    for (int off = 32; off > 0; off >>= 1) lmin = min(lmin, __shfl_down(lmin, off));
    __syncthreads();
    if ((t & 63) == 0) atomicMin(&headSh, lmin);
    __syncthreads();
    const int head = headSh;

    for (int rr = t; rr < RPER; rr += 256) {
        const int base = (g * RPER + rr) * 3;
        atomicAdd(&Am[rel[base + 1] - head][rel[base + 2] - head],
                  atten[g * RPER + rr]);
    }
    __syncthreads();

    for (int idx = t; idx < 4096; idx += 256) {
        const int i = idx >> 6, j = idx & 63;
        float v = 1.f / (1.f + expf(-Am[i][j]));
        if (i == j) v = 0.f;
        Am[i][j] = v;
    }
    __syncthreads();

    if (t < 64) {
        float sum = 0.f;
        for (int k = 0; k < 64; ++k) sum += Am[t][k];
        S[t] = sum;
    }
    __syncthreads();

    float* outg = Anorm + (size_t)g * 4096;
    for (int idx = t; idx < 4096; idx += 256) {
        const int j = idx & 63;
        outg[idx] = ((const float*)Am)[idx] / S[j];
    }
}

// ---------------------------------------------------------------------------
// 4 rows per block; one 512 KB P-slice read serves 4 rows. 256 blocks,
// XCD-grouped. h = A*P1 + A^T*P2 + b -> LN -> relu -> bf16.
// ---------------------------------------------------------------------------
__global__ __launch_bounds__(256) void amult_ln4(
    const float* __restrict__ Anorm, const float* __restrict__ P,
    const float* __restrict__ w1b, const float* __restrict__ gamma,
    const float* __restrict__ beta, __hip_bfloat16* __restrict__ hb)
{
    const int b = blockIdx.x;
    const int wg = (b & 7) * 32 + (b >> 3);
    const int g = wg >> 4;
    const int grp = wg & 15;
    const int t = threadIdx.x;

    __shared__ float Ar[4][64], Ac[4][64];
    {
        const int r = t >> 6, j = t & 63;
        Ar[r][j] = Anorm[(size_t)g * 4096 + (grp * 4 + r) * 64 + j];
        Ac[r][j] = Anorm[(size_t)g * 4096 + j * 64 + grp * 4 + r];
    }
    __syncthreads();

    const float* pg = P + (size_t)g * 64 * 2048;
    const int c = t << 2;
    float4 v0 = {0,0,0,0}, v1 = v0, v2 = v0, v3 = v0;
    for (int j = 0; j < 64; ++j) {
        float4 p1 = *(const float4*)(pg + (size_t)j * 2048 + c);
        float4 p2 = *(const float4*)(pg + (size_t)j * 2048 + 1024 + c);
        fma4(v0, Ar[0][j], p1); fma4(v0, Ac[0][j], p2);
        fma4(v1, Ar[1][j], p1); fma4(v1, Ac[1][j], p2);
        fma4(v2, Ar[2][j], p1); fma4(v2, Ac[2][j], p2);
        fma4(v3, Ar[3][j], p1); fma4(v3, Ac[3][j], p2);
    }
    float4 bb = *(const float4*)(w1b + c);
    v0.x += bb.x; v0.y += bb.y; v0.z += bb.z; v0.w += bb.w;
    v1.x += bb.x; v1.y += bb.y; v1.z += bb.z; v1.w += bb.w;
    v2.x += bb.x; v2.y += bb.y; v2.z += bb.z; v2.w += bb.w;
    v3.x += bb.x; v3.y += bb.y; v3.z += bb.z; v3.w += bb.w;

    float s0 = v0.x + v0.y + v0.z + v0.w;
    float s1 = v1.x + v1.y + v1.z + v1.w;
    float s2 = v2.x + v2.y + v2.z + v2.w;
    float s3 = v3.x + v3.y + v3.z + v3.w;
    float q0 = v0.x*v0.x + v0.y*v0.y + v0.z*v0.z + v0.w*v0.w;
    float q1 = v1.x*v1.x + v1.y*v1.y + v1.z*v1.z + v1.w*v1.w;
    float q2 = v2.x*v2.x + v2.y*v2.y + v2.z*v2.z + v2.w*v2.w;
    float q3 = v3.x*v3.x + v3.y*v3.y + v3.z*v3.z + v3.w*v3.w;
    for (int off = 32; off > 0; off >>= 1) {
        s0 += __shfl_down(s0, off); s1 += __shfl_down(s1, off);
        s2 += __shfl_down(s2, off); s3 += __shfl_down(s3, off);
        q0 += __shfl_down(q0, off); q1 += __shfl_down(q1, off);
        q2 += __shfl_down(q2, off); q3 += __shfl_down(q3, off);
    }
    __shared__ float rs[4][4], rq[4][4];
    if ((t & 63) == 0) {
        const int w = t >> 6;
        rs[w][0] = s0; rs[w][1] = s1; rs[w][2] = s2; rs[w][3] = s3;
        rq[w][0] = q0; rq[w][1] = q1; rq[w][2] = q2; rq[w][3] = q3;
    }
    __syncthreads();
    float4 g4 = *(const float4*)(gamma + c);
    float4 b4 = *(const float4*)(beta + c);
    const size_t rowBase = (size_t)(g * 64 + grp * 4) * DT + c;
    float4 vv[4] = {v0, v1, v2, v3};
#pragma unroll
    for (int r = 0; r < 4; ++r) {
        const float tot  = rs[0][r] + rs[1][r] + rs[2][r] + rs[3][r];
        const float tot2 = rq[0][r] + rq[1][r] + rq[2][r] + rq[3][r];
        const float mu   = tot * (1.f / DT);
        const float var  = tot2 * (1.f / DT) - mu * mu;
        const float rstd = rsqrtf(var + 1e-5f);
        float4 o;
        o.x = fmaxf(fmaf((vv[r].x - mu) * rstd, g4.x, b4.x), 0.f);
        o.y = fmaxf(fmaf((vv[r].y - mu) * rstd, g4.y, b4.y), 0.f);
        o.z = fmaxf(fmaf((vv[r].z - mu) * rstd, g4.z, b4.z), 0.f);
        o.w = fmaxf(fmaf((vv[r].w - mu) * rstd, g4.w, b4.w), 0.f);
        st4bf(hb + rowBase + (size_t)r * DT, o);
    }
}

// ---------------------------------------------------------------------------
extern "C" void kernel_launch(void* const* d_in, const int* in_sizes, int n_in,
                              void* d_out, int out_size, void* d_ws, size_t ws_size,
                              hipStream_t stream)
{
    const float* obj   = (const float*)d_in[0];
    const float* phr   = (const float*)d_in[1];
    const int*   rel   = (const int*)d_in[3];
    const float* Ws_w  = (const float*)d_in[5];
    const float* Ws_b  = (const float*)d_in[6];
    const float* Wo_w  = (const float*)d_in[7];
    const float* Wo_b  = (const float*)d_in[8];
    const float* Ww_w  = (const float*)d_in[9];
    const float* Ww_b  = (const float*)d_in[10];
    const float* Wc_w  = (const float*)d_in[11];
    const float* Wc_b  = (const float*)d_in[12];
    const float* Wt1_w = (const float*)d_in[13];
    const float* Wt1_b = (const float*)d_in[14];
    const float* ln_g  = (const float*)d_in[15];
    const float* ln_b  = (const float*)d_in[16];
    const float* Wt2_w = (const float*)d_in[17];
    const float* Wt2_b = (const float*)d_in[18];
    float* out = (float*)d_out;

    float* ws = (float*)d_ws;
    // workspace (float units), peak ~130.4 MB:
    __hip_bfloat16* wbuf    = (__hip_bfloat16*)ws;              // Ws|Wo|Wc bf16 — dead after fused
    __hip_bfloat16* h_bf    = (__hip_bfloat16*)ws;              // alias dead wbuf
    __hip_bfloat16* obj_bf  = (__hip_bfloat16*)(ws + 20971520); // dead after fused
    float* Pbuf             = ws + 20971520;                    // alias dead obj_bf
    __hip_bfloat16* wswo_bf = (__hip_bfloat16*)(ws + 23068672); // 1024x8192 bf16
    __hip_bfloat16* conv_bf = (__hip_bfloat16*)(ws + 27262976); // 1024x2048 bf16
    __hip_bfloat16* wt1r    = (__hip_bfloat16*)(ws + 28311552); // 2048x2048 bf16
    __hip_bfloat16* wt2b    = (__hip_bfloat16*)(ws + 30408704); // 4096x1024 bf16
    float* atten  = ws + 32505856;                              // 8192
    float* Anorm  = ws + 32514048;                              // 65536
    float* cbias  = ws + 32579584;                              // 10240

    const dim3 blk(256);

    // 1. single cast dispatch: obj, Ws, Wo, Wc, Wt1r, Wt2 -> bf16 + biases
    cast_all<<<dim3(26664), blk, 0, stream>>>(
        obj, obj_bf, Ws_w, Wo_w, Wc_w, wbuf, Wt1_w, wt1r, Wt2_w, wt2b,
        Ws_b, Wo_b, Wc_b, cbias);

    // 2. fused ws|wo|conv GEMM — 4-wave 128x128-wave-tile minimal-sync 256²
    gemm8v6<<<dim3(160), blk, 0, stream>>>(
        (const ushort*)obj_bf, (const ushort*)wbuf, cbias,
        wswo_bf, conv_bf, NTOT, D_);

    // 3. atten (bf16 ws/wo) + A build
    atten_kernel<<<dim3(RTOT), blk, 0, stream>>>(
        (const ushort*)wswo_bf, phr, rel, Ww_w, Ww_b, atten);
    build_A<<<dim3(NIMG), blk, 0, stream>>>(rel, atten, Anorm);

    // 4. P = conv_bf @ wt1r^T (1024 x 2048, K=2048) -> Pbuf
    gemm_p2<64, 64><<<dim3(512), blk, 0, stream>>>(
        (const ushort*)conv_bf, (const ushort*)wt1r, nullptr, nullptr,
        Pbuf, NTOT, DC, DC, 0);

    // 5. h = A*P1 + A^T*P2 + b, LN, relu -> bf16 (4 rows/block)
    amult_ln4<<<dim3(256), blk, 0, stream>>>(Anorm, Pbuf, Wt1_b, ln_g, ln_b, h_bf);

    // 6. out = relu(obj + h @ Wt2^T + b)
    gemm_p2<64, 128><<<dim3(512), blk, 0, stream>>>(
        (const ushort*)h_bf, (const ushort*)wt2b, Wt2_b, obj,
        out, NTOT, DT, D_, 2);
}

// Round 19
// 267.509 us; speedup vs baseline: 1.0618x; 1.0618x over previous
//
#include <hip/hip_runtime.h>
#include <hip/hip_bf16.h>
#include <math.h>

#define D_   4096
#define NIMG 16
#define NPER 64
#define RPER 512
#define NTOT 1024
#define RTOT 8192
#define DC   2048
#define DT   1024
#define LDW  8192    // wswo_bf row stride (4096 ws | 4096 wo), bf16

typedef __attribute__((ext_vector_type(4))) float f32x4;
typedef __attribute__((ext_vector_type(8))) short bf16x8;

#define GLD16(gp, lp) __builtin_amdgcn_global_load_lds( \
    (const __attribute__((address_space(1))) unsigned int*)(gp), \
    (__attribute__((address_space(3))) unsigned int*)(lp), 16, 0, 0)

template<int N> __device__ __forceinline__ void waitvm() {
    asm volatile("s_waitcnt vmcnt(%0)" :: "n"(N) : "memory");
}

__device__ __forceinline__ void fma4(float4& d, float s, const float4 c) {
    d.x = fmaf(s, c.x, d.x); d.y = fmaf(s, c.y, d.y);
    d.z = fmaf(s, c.z, d.z); d.w = fmaf(s, c.w, d.w);
}
__device__ __forceinline__ void st4bf(__hip_bfloat16* p, float4 v) {
    union { __hip_bfloat16 h[4]; ushort4 u; } cv;
    cv.h[0] = __float2bfloat16(v.x); cv.h[1] = __float2bfloat16(v.y);
    cv.h[2] = __float2bfloat16(v.z); cv.h[3] = __float2bfloat16(v.w);
    *(ushort4*)p = cv.u;
}
__device__ __forceinline__ float bf2f(ushort u) {
    union { float f; unsigned int i; } c; c.i = (unsigned int)u << 16; return c.f;
}
__device__ __forceinline__ ushort f2bfu(float v) {
    union { __hip_bfloat16 h; ushort u; } c; c.h = __float2bfloat16(v); return c.u;
}

// ---------------------------------------------------------------------------
// ONE up-front dispatch: cast obj/Ws/Wo/Wc/Wt1(rearranged)/Wt2 -> bf16,
// concat biases. Sources are read-once -> non-temporal loads.
// wt1r[r][c] = Wt1[r&1023][(r>>10)*2048 + c]
// ---------------------------------------------------------------------------
__global__ __launch_bounds__(256) void cast_all(
    const float* __restrict__ obj, __hip_bfloat16* __restrict__ obj_bf,
    const float* __restrict__ Ws, const float* __restrict__ Wo,
    const float* __restrict__ Wc, __hip_bfloat16* __restrict__ wbuf,
    const float* __restrict__ Wt1, __hip_bfloat16* __restrict__ wt1r,
    const float* __restrict__ Wt2, __hip_bfloat16* __restrict__ wt2b,
    const float* __restrict__ b0, const float* __restrict__ b1,
    const float* __restrict__ b2, float* __restrict__ cb)
{
    const int b = blockIdx.x;
    const int t = threadIdx.x;
    if (b >= 26624) {                                    // bias concat
        const int i = (b - 26624) * 256 + t;             // 0..10239
        float v;
        if (i < 4096) v = b0[i];
        else if (i < 8192) v = b1[i - 4096];
        else v = b2[i - 8192];
        cb[i] = v;
        return;
    }
    const float* s; __hip_bfloat16* d;
    if (b < 2048)       { s = obj + (size_t)b * 2048;            d = obj_bf + (size_t)b * 2048; }
    else if (b < 10240) { const int rb = b - 2048;  s = Ws + (size_t)rb * 2048; d = wbuf + (size_t)rb * 2048; }
    else if (b < 18432) { const int rb = b - 10240; s = Wo + (size_t)rb * 2048; d = wbuf + 16777216 + (size_t)rb * 2048; }
    else if (b < 22528) { const int rb = b - 18432; s = Wc + (size_t)rb * 2048; d = wbuf + 33554432 + (size_t)rb * 2048; }
    else if (b < 24576) { const int r = b - 22528;                // wt1 rearranged
                          s = Wt1 + (size_t)(r & 1023) * 4096 + (r >> 10) * 2048;
                          d = wt1r + (size_t)r * 2048; }
    else                { const int rb = b - 24576; s = Wt2 + (size_t)rb * 2048; d = wt2b + (size_t)rb * 2048; }
    const int i = t * 8;
    f32x4 v0 = __builtin_nontemporal_load((const f32x4*)(s + i));
    f32x4 v1 = __builtin_nontemporal_load((const f32x4*)(s + i + 4));
    union { __hip_bfloat16 h[8]; ushort4 u[2]; } cv;
    cv.h[0] = __float2bfloat16(v0[0]); cv.h[1] = __float2bfloat16(v0[1]);
    cv.h[2] = __float2bfloat16(v0[2]); cv.h[3] = __float2bfloat16(v0[3]);
    cv.h[4] = __float2bfloat16(v1[0]); cv.h[5] = __float2bfloat16(v1[1]);
    cv.h[6] = __float2bfloat16(v1[2]); cv.h[7] = __float2bfloat16(v1[3]);
    *(ushort4*)(d + i)     = cv.u[0];
    *(ushort4*)(d + i + 4) = cv.u[1];
}

// ---------------------------------------------------------------------------
// Fused GEMM (ws|wo|conv) v5 — 4 LDS buffers / 3-tiles-ahead staging
// (measured best: 123-127 µs). 256x256 tile, 512 thr = 8 waves (2M x 4N),
// wave tile 128x64, BK=32. Counted vmcnt(8) once per K-tile (tiles T+2,T+3
// in flight; T+1 resident), ONE s_barrier per tile. Race-free: buf
// (T+3)%4 == (T-1)%4, readers done before barrier(T-1). Tail 8->4->0.
// Swizzle: phys 16B slot p of row r holds K-quarter p ^ ((r>>1)&3).
// Epilogue: per-wave LDS-bounce -> contiguous 16B bf16 stores.
// ---------------------------------------------------------------------------
__global__ __launch_bounds__(512, 1) void gemm8v5(
    const ushort* __restrict__ A, const ushort* __restrict__ B,
    const float* __restrict__ bias,
    __hip_bfloat16* __restrict__ C2, __hip_bfloat16* __restrict__ C3,
    int M, int K)
{
    __shared__ ushort sh[4][16384];   // per buf: A 8192 ushorts | B 8192

    const int t = threadIdx.x;
    const int lane = t & 63;
    const int wid = t >> 6;
    const int wm = wid >> 2, wn = wid & 3;

    const int MT = M >> 8;                                // 4
    const int G = gridDim.x;                              // 160 (G%8==0)
    const int wgid = (blockIdx.x & 7) * (G >> 3) + (blockIdx.x >> 3);
    const int nt = wgid / MT, mt = wgid % MT;
    const int bm = mt * 256, bn = nt * 256;

    const int rA0 = t >> 2,          qA0 = (t & 3) ^ ((rA0 >> 1) & 3);
    const int rA1 = (t + 512) >> 2,  qA1 = (t & 3) ^ ((rA1 >> 1) & 3);
    const ushort* gA0 = A + (size_t)(bm + rA0) * K + qA0 * 8;
    const ushort* gA1 = A + (size_t)(bm + rA1) * K + qA1 * 8;
    const ushort* gB0 = B + (size_t)(bn + rA0) * K + qA0 * 8;
    const ushort* gB1 = B + (size_t)(bn + rA1) * K + qA1 * 8;
    const int dA0 = t * 8, dA1 = (t + 512) * 8;
    const int dB0 = 8192 + t * 8, dB1 = 8192 + (t + 512) * 8;

    const int sx = ((lane >> 4) ^ ((lane >> 1) & 3)) * 8;
    int aoff[8], boff[4];
#pragma unroll
    for (int m = 0; m < 8; ++m)
        aoff[m] = (wm * 128 + m * 16 + (lane & 15)) * 32 + sx;
#pragma unroll
    for (int n = 0; n < 4; ++n)
        boff[n] = 8192 + (wn * 64 + n * 16 + (lane & 15)) * 32 + sx;

    f32x4 acc[8][4] = {};
    const int NT = K >> 5;   // 128

    // prologue: stage tiles 0, 1, 2
#pragma unroll
    for (int p = 0; p < 3; ++p) {
        const int kp = p << 5;
        GLD16(gA0 + kp, &sh[p][dA0]); GLD16(gA1 + kp, &sh[p][dA1]);
        GLD16(gB0 + kp, &sh[p][dB0]); GLD16(gB1 + kp, &sh[p][dB1]);
    }
    waitvm<8>();                      // tile 0 resident; 1,2 in flight
    __builtin_amdgcn_sched_barrier(0);
    __builtin_amdgcn_s_barrier();
    __builtin_amdgcn_sched_barrier(0);

    for (int T = 0; T < NT; ++T) {
        const ushort* lb = sh[T & 3];
        ushort* nb = sh[(T + 3) & 3];
        const int kpos = (T + 3) << 5;

        if (T + 3 < NT) {
            GLD16(gA0 + kpos, nb + dA0); GLD16(gA1 + kpos, nb + dA1);
            GLD16(gB0 + kpos, nb + dB0); GLD16(gB1 + kpos, nb + dB1);
        }

        bf16x8 bv[4], af[8];
#pragma unroll
        for (int n = 0; n < 4; ++n) bv[n] = *(const bf16x8*)(lb + boff[n]);
#pragma unroll
        for (int m = 0; m < 8; ++m) af[m] = *(const bf16x8*)(lb + aoff[m]);
        __builtin_amdgcn_s_setprio(1);
#pragma unroll
        for (int m = 0; m < 8; ++m)
#pragma unroll
            for (int n = 0; n < 4; ++n)
                acc[m][n] = __builtin_amdgcn_mfma_f32_16x16x32_bf16(
                    af[m], bv[n], acc[m][n], 0, 0, 0);
        __builtin_amdgcn_s_setprio(0);

        __builtin_amdgcn_sched_barrier(0);
        if (T + 3 < NT) waitvm<8>();          // tile T+1 resident
        else if (T + 2 < NT) waitvm<4>();
        else waitvm<0>();
        __builtin_amdgcn_sched_barrier(0);
        __builtin_amdgcn_s_barrier();
        __builtin_amdgcn_sched_barrier(0);
    }

    ushort* patch = ((ushort*)sh) + wid * (64 * 72);
    const bool doRelu = (bn >= 8192);
    const int lcol8 = (lane & 7) * 8;
#pragma unroll
    for (int chunk = 0; chunk < 2; ++chunk) {
#pragma unroll
        for (int m2 = 0; m2 < 4; ++m2) {
            const int m = chunk * 4 + m2;
#pragma unroll
            for (int n = 0; n < 4; ++n) {
                const float bz = bias[bn + wn * 64 + n * 16 + (lane & 15)];
#pragma unroll
                for (int rg = 0; rg < 4; ++rg) {
                    float v = acc[m][n][rg] + bz;
                    if (doRelu) v = fmaxf(v, 0.f);
                    const int lr = m2 * 16 + ((lane >> 4) << 2) + rg;
                    const int lc = n * 16 + (lane & 15);
                    patch[lr * 72 + lc] = f2bfu(v);
                }
            }
        }
#pragma unroll
        for (int m2 = 0; m2 < 4; ++m2) {
#pragma unroll
            for (int pass = 0; pass < 2; ++pass) {
                const int lr = m2 * 16 + pass * 8 + (lane >> 3);
                uint4 v4 = *(const uint4*)(patch + lr * 72 + lcol8);
                const int grow = bm + wm * 128 + chunk * 64 + lr;
                const int gcol = bn + wn * 64 + lcol8;
                if (gcol < 8192)
                    *(uint4*)((ushort*)C2 + (size_t)grow * LDW + gcol) = v4;
                else
                    *(uint4*)((ushort*)C3 + (size_t)grow * 2048 + (gcol - 8192)) = v4;
            }
        }
    }
}

// ---------------------------------------------------------------------------
// MFMA GEMM (round-4 schedule + r9 swizzle) — used for P-GEMM and wt2.
// mode: 0 = +bias (nullable), f32 out; 2 = relu(resid + . + bias), f32 out
// ---------------------------------------------------------------------------
template<int BM, int BN>
__global__ __launch_bounds__(256) void gemm_p2(
    const ushort* __restrict__ A, const ushort* __restrict__ B,
    const float* __restrict__ bias, const float* __restrict__ resid,
    float* __restrict__ C, int M, int K, int ldc, int mode)
{
    constexpr int MREP = BM / 32;
    constexpr int NREP = BN / 32;
    constexpr int SLOTS = (BM + BN) * 4;
    constexpr int NPW = SLOTS / 256;
    constexpr int BUFE = SLOTS * 8;

    __shared__ ushort lds[3][BUFE];

    const int t = threadIdx.x;
    const int lane = t & 63;
    const int wid = t >> 6;
    const int wr = wid >> 1, wc = wid & 1;

    const int MT = M / BM;
    const int G = gridDim.x;
    const int bid = blockIdx.x;
    const int wgid = (bid & 7) * (G >> 3) + (bid >> 3);
    const int nt = wgid / MT, mt = wgid % MT;
    const int bm = mt * BM, bn = nt * BN;

    const ushort* gp[NPW];
    int loff[NPW];
#pragma unroll
    for (int i = 0; i < NPW; ++i) {
        const int slot = i * 256 + t;
        const bool isA = slot < BM * 4;
        const int s2 = isA ? slot : slot - BM * 4;
        const int row = s2 >> 2;
        const int q = (s2 & 3) ^ ((row >> 1) & 3);
        gp[i] = (isA ? A + (size_t)(bm + row) * K : B + (size_t)(bn + row) * K) + q * 8;
        loff[i] = slot * 8;
    }

    auto stage = [&](int b, int kpos) {
#pragma unroll
        for (int i = 0; i < NPW; ++i) GLD16(gp[i] + kpos, &lds[b][loff[i]]);
    };

    int aoff[MREP], boff[NREP];
    const int sx = (((lane >> 4) ^ ((lane >> 1) & 3))) << 3;
#pragma unroll
    for (int m = 0; m < MREP; ++m)
        aoff[m] = (wr * (BM / 2) + (lane & 15) + m * 16) * 32 + sx;
#pragma unroll
    for (int n = 0; n < NREP; ++n)
        boff[n] = BM * 32 + (wc * (BN / 2) + (lane & 15) + n * 16) * 32 + sx;

    f32x4 acc[MREP][NREP] = {};

    const int NT = K >> 5;
    stage(0, 0);
    stage(1, 32);
    if constexpr (NPW == 2) waitvm<2>();
    else if constexpr (NPW == 3) waitvm<3>();
    else waitvm<4>();
    __builtin_amdgcn_sched_barrier(0);
    __builtin_amdgcn_s_barrier();
    __builtin_amdgcn_sched_barrier(0);

    for (int tt = 0; tt < NT; ++tt) {
        const bool pf = (tt + 2 < NT);
        if (pf) stage((tt + 2) % 3, (tt + 2) << 5);
        __builtin_amdgcn_sched_barrier(0);

        const ushort* lb = lds[tt % 3];
        bf16x8 af[MREP], bfv[NREP];
#pragma unroll
        for (int m = 0; m < MREP; ++m) af[m] = *(const bf16x8*)(lb + aoff[m]);
#pragma unroll
        for (int n = 0; n < NREP; ++n) bfv[n] = *(const bf16x8*)(lb + boff[n]);
#pragma unroll
        for (int m = 0; m < MREP; ++m)
#pragma unroll
            for (int n = 0; n < NREP; ++n)
                acc[m][n] = __builtin_amdgcn_mfma_f32_16x16x32_bf16(
                    af[m], bfv[n], acc[m][n], 0, 0, 0);

        __builtin_amdgcn_sched_barrier(0);
        if (pf) {
            if constexpr (NPW == 2) waitvm<2>();
            else if constexpr (NPW == 3) waitvm<3>();
            else waitvm<4>();
        } else {
            waitvm<0>();
        }
        __builtin_amdgcn_sched_barrier(0);
        __builtin_amdgcn_s_barrier();
        __builtin_amdgcn_sched_barrier(0);
    }

    const int col0 = bn + wc * (BN / 2) + (lane & 15);
    const int row0 = bm + wr * (BM / 2) + ((lane >> 4) << 2);
#pragma unroll
    for (int m = 0; m < MREP; ++m) {
#pragma unroll
        for (int n = 0; n < NREP; ++n) {
            const int cn = col0 + n * 16;
            const float bz = bias ? bias[cn] : 0.f;
#pragma unroll
            for (int rg = 0; rg < 4; ++rg) {
                const int gm = row0 + m * 16 + rg;
                float v = acc[m][n][rg] + bz;
                if (mode == 2)
                    v = fmaxf(v + resid[(size_t)gm * ldc + cn], 0.f);
                C[(size_t)gm * ldc + cn] = v;
            }
        }
    }
}

// ---------------------------------------------------------------------------
// atten[r] = sum_d ws[s[r],d] * wo[o[r],d] * phr[r,d] * Www[d]  + Wwb
// ws/wo bf16 in wswo (row stride LDW). XCD-grouped per image.
// ---------------------------------------------------------------------------
__global__ __launch_bounds__(256) void atten_kernel(
    const ushort* __restrict__ wswo, const float* __restrict__ phr,
    const int* __restrict__ rel, const float* __restrict__ Www,
    const float* __restrict__ Wwb, float* __restrict__ atten)
{
    const int r = (blockIdx.x & 7) * 1024 + (blockIdx.x >> 3);
    const int s = rel[r * 3 + 1], o = rel[r * 3 + 2];
    const int t = threadIdx.x;
    const ushort* pws = wswo + (size_t)s * LDW;
    const ushort* pwo = wswo + (size_t)o * LDW + 4096;
    const float*  pph = phr + (size_t)r * D_;
    float sum = 0.f;
#pragma unroll
    for (int half = 0; half < 2; ++half) {
        const int q = t * 8 + half * 2048;
        ushort4 w0 = *(const ushort4*)(pws + q);
        ushort4 w1 = *(const ushort4*)(pws + q + 4);
        ushort4 u0 = *(const ushort4*)(pwo + q);
        ushort4 u1 = *(const ushort4*)(pwo + q + 4);
        float4 p0 = *(const float4*)(pph + q);
        float4 p1 = *(const float4*)(pph + q + 4);
        float4 g0 = *(const float4*)(Www + q);
        float4 g1 = *(const float4*)(Www + q + 4);
        sum += bf2f(w0.x) * bf2f(u0.x) * p0.x * g0.x
             + bf2f(w0.y) * bf2f(u0.y) * p0.y * g0.y
             + bf2f(w0.z) * bf2f(u0.z) * p0.z * g0.z
             + bf2f(w0.w) * bf2f(u0.w) * p0.w * g0.w
             + bf2f(w1.x) * bf2f(u1.x) * p1.x * g1.x
             + bf2f(w1.y) * bf2f(u1.y) * p1.y * g1.y
             + bf2f(w1.z) * bf2f(u1.z) * p1.z * g1.z
             + bf2f(w1.w) * bf2f(u1.w) * p1.w * g1.w;
    }
    for (int off = 32; off > 0; off >>= 1) sum += __shfl_down(sum, off);
    __shared__ float red[4];
    if ((t & 63) == 0) red[t >> 6] = sum;
    __syncthreads();
    if (t == 0) atten[r] = red[0] + red[1] + red[2] + red[3] + Wwb[0];
}

// ---------------------------------------------------------------------------
__global__ __launch_bounds__(256) void build_A(
    const int* __restrict__ rel, const float* __restrict__ atten,
    float* __restrict__ Anorm)
{
    const int g = blockIdx.x;
    const int t = threadIdx.x;
    __shared__ float Am[64][64];
    __shared__ float S[64];
    __shared__ int headSh;
    for (int i = t; i < 4096; i += 256) ((float*)Am)[i] = 0.f;
    if (t == 0) headSh = 0x7fffffff;

    int lmin = 0x7fffffff;
    for (int rr = t; rr < RPER; rr += 256) {
        const int base = (g * RPER + rr) * 3;
        lmin = min(lmin, min(rel[base + 1], rel[base + 2]));
    }
    for (int off = 32; off > 0; off >>= 1) lmin = min(lmin, __shfl_down(lmin, off));
    __syncthreads();
    if ((t & 63) == 0) atomicMin(&headSh, lmin);
    __syncthreads();
    const int head = headSh;

    for (int rr = t; rr < RPER; rr += 256) {
        const int base = (g * RPER + rr) * 3;
        atomicAdd(&Am[rel[base + 1] - head][rel[base + 2] - head],
                  atten[g * RPER + rr]);
    }
    __syncthreads();

    for (int idx = t; idx < 4096; idx += 256) {
        const int i = idx >> 6, j = idx & 63;
        float v = 1.f / (1.f + expf(-Am[i][j]));
        if (i == j) v = 0.f;
        Am[i][j] = v;
    }
    __syncthreads();

    if (t < 64) {
        float sum = 0.f;
        for (int k = 0; k < 64; ++k) sum += Am[t][k];
        S[t] = sum;
    }
    __syncthreads();

    float* outg = Anorm + (size_t)g * 4096;
    for (int idx = t; idx < 4096; idx += 256) {
        const int j = idx & 63;
        outg[idx] = ((const float*)Am)[idx] / S[j];
    }
}

// ---------------------------------------------------------------------------
// 4 rows per block; one 512 KB P-slice read serves 4 rows. 256 blocks,
// XCD-grouped. h = A*P1 + A^T*P2 + b -> LN -> relu -> bf16.
// ---------------------------------------------------------------------------
__global__ __launch_bounds__(256) void amult_ln4(
    const float* __restrict__ Anorm, const float* __restrict__ P,
    const float* __restrict__ w1b, const float* __restrict__ gamma,
    const float* __restrict__ beta, __hip_bfloat16* __restrict__ hb)
{
    const int b = blockIdx.x;
    const int wg = (b & 7) * 32 + (b >> 3);
    const int g = wg >> 4;
    const int grp = wg & 15;
    const int t = threadIdx.x;

    __shared__ float Ar[4][64], Ac[4][64];
    {
        const int r = t >> 6, j = t & 63;
        Ar[r][j] = Anorm[(size_t)g * 4096 + (grp * 4 + r) * 64 + j];
        Ac[r][j] = Anorm[(size_t)g * 4096 + j * 64 + grp * 4 + r];
    }
    __syncthreads();

    const float* pg = P + (size_t)g * 64 * 2048;
    const int c = t << 2;
    float4 v0 = {0,0,0,0}, v1 = v0, v2 = v0, v3 = v0;
    for (int j = 0; j < 64; ++j) {
        float4 p1 = *(const float4*)(pg + (size_t)j * 2048 + c);
        float4 p2 = *(const float4*)(pg + (size_t)j * 2048 + 1024 + c);
        fma4(v0, Ar[0][j], p1); fma4(v0, Ac[0][j], p2);
        fma4(v1, Ar[1][j], p1); fma4(v1, Ac[1][j], p2);
        fma4(v2, Ar[2][j], p1); fma4(v2, Ac[2][j], p2);
        fma4(v3, Ar[3][j], p1); fma4(v3, Ac[3][j], p2);
    }
    float4 bb = *(const float4*)(w1b + c);
    v0.x += bb.x; v0.y += bb.y; v0.z += bb.z; v0.w += bb.w;
    v1.x += bb.x; v1.y += bb.y; v1.z += bb.z; v1.w += bb.w;
    v2.x += bb.x; v2.y += bb.y; v2.z += bb.z; v2.w += bb.w;
    v3.x += bb.x; v3.y += bb.y; v3.z += bb.z; v3.w += bb.w;

    float s0 = v0.x + v0.y + v0.z + v0.w;
    float s1 = v1.x + v1.y + v1.z + v1.w;
    float s2 = v2.x + v2.y + v2.z + v2.w;
    float s3 = v3.x + v3.y + v3.z + v3.w;
    float q0 = v0.x*v0.x + v0.y*v0.y + v0.z*v0.z + v0.w*v0.w;
    float q1 = v1.x*v1.x + v1.y*v1.y + v1.z*v1.z + v1.w*v1.w;
    float q2 = v2.x*v2.x + v2.y*v2.y + v2.z*v2.z + v2.w*v2.w;
    float q3 = v3.x*v3.x + v3.y*v3.y + v3.z*v3.z + v3.w*v3.w;
    for (int off = 32; off > 0; off >>= 1) {
        s0 += __shfl_down(s0, off); s1 += __shfl_down(s1, off);
        s2 += __shfl_down(s2, off); s3 += __shfl_down(s3, off);
        q0 += __shfl_down(q0, off); q1 += __shfl_down(q1, off);
        q2 += __shfl_down(q2, off); q3 += __shfl_down(q3, off);
    }
    __shared__ float rs[4][4], rq[4][4];
    if ((t & 63) == 0) {
        const int w = t >> 6;
        rs[w][0] = s0; rs[w][1] = s1; rs[w][2] = s2; rs[w][3] = s3;
        rq[w][0] = q0; rq[w][1] = q1; rq[w][2] = q2; rq[w][3] = q3;
    }
    __syncthreads();
    float4 g4 = *(const float4*)(gamma + c);
    float4 b4 = *(const float4*)(beta + c);
    const size_t rowBase = (size_t)(g * 64 + grp * 4) * DT + c;
    float4 vv[4] = {v0, v1, v2, v3};
#pragma unroll
    for (int r = 0; r < 4; ++r) {
        const float tot  = rs[0][r] + rs[1][r] + rs[2][r] + rs[3][r];
        const float tot2 = rq[0][r] + rq[1][r] + rq[2][r] + rq[3][r];
        const float mu   = tot * (1.f / DT);
        const float var  = tot2 * (1.f / DT) - mu * mu;
        const float rstd = rsqrtf(var + 1e-5f);
        float4 o;
        o.x = fmaxf(fmaf((vv[r].x - mu) * rstd, g4.x, b4.x), 0.f);
        o.y = fmaxf(fmaf((vv[r].y - mu) * rstd, g4.y, b4.y), 0.f);
        o.z = fmaxf(fmaf((vv[r].z - mu) * rstd, g4.z, b4.z), 0.f);
        o.w = fmaxf(fmaf((vv[r].w - mu) * rstd, g4.w, b4.w), 0.f);
        st4bf(hb + rowBase + (size_t)r * DT, o);
    }
}

// ---------------------------------------------------------------------------
extern "C" void kernel_launch(void* const* d_in, const int* in_sizes, int n_in,
                              void* d_out, int out_size, void* d_ws, size_t ws_size,
                              hipStream_t stream)
{
    const float* obj   = (const float*)d_in[0];
    const float* phr   = (const float*)d_in[1];
    const int*   rel   = (const int*)d_in[3];
    const float* Ws_w  = (const float*)d_in[5];
    const float* Ws_b  = (const float*)d_in[6];
    const float* Wo_w  = (const float*)d_in[7];
    const float* Wo_b  = (const float*)d_in[8];
    const float* Ww_w  = (const float*)d_in[9];
    const float* Ww_b  = (const float*)d_in[10];
    const float* Wc_w  = (const float*)d_in[11];
    const float* Wc_b  = (const float*)d_in[12];
    const float* Wt1_w = (const float*)d_in[13];
    const float* Wt1_b = (const float*)d_in[14];
    const float* ln_g  = (const float*)d_in[15];
    const float* ln_b  = (const float*)d_in[16];
    const float* Wt2_w = (const float*)d_in[17];
    const float* Wt2_b = (const float*)d_in[18];
    float* out = (float*)d_out;

    float* ws = (float*)d_ws;
    // workspace (float units), peak ~130.4 MB:
    __hip_bfloat16* wbuf    = (__hip_bfloat16*)ws;              // Ws|Wo|Wc bf16 — dead after fused
    __hip_bfloat16* h_bf    = (__hip_bfloat16*)ws;              // alias dead wbuf
    __hip_bfloat16* obj_bf  = (__hip_bfloat16*)(ws + 20971520); // dead after fused
    float* Pbuf             = ws + 20971520;                    // alias dead obj_bf
    __hip_bfloat16* wswo_bf = (__hip_bfloat16*)(ws + 23068672); // 1024x8192 bf16
    __hip_bfloat16* conv_bf = (__hip_bfloat16*)(ws + 27262976); // 1024x2048 bf16
    __hip_bfloat16* wt1r    = (__hip_bfloat16*)(ws + 28311552); // 2048x2048 bf16
    __hip_bfloat16* wt2b    = (__hip_bfloat16*)(ws + 30408704); // 4096x1024 bf16
    float* atten  = ws + 32505856;                              // 8192
    float* Anorm  = ws + 32514048;                              // 65536
    float* cbias  = ws + 32579584;                              // 10240

    const dim3 blk(256);

    // 1. single cast dispatch: obj, Ws, Wo, Wc, Wt1r, Wt2 -> bf16 + biases
    cast_all<<<dim3(26664), blk, 0, stream>>>(
        obj, obj_bf, Ws_w, Wo_w, Wc_w, wbuf, Wt1_w, wt1r, Wt2_w, wt2b,
        Ws_b, Wo_b, Wc_b, cbias);

    // 2. fused ws|wo|conv GEMM — 4-buffer 3-deep minimal-sync 256²
    gemm8v5<<<dim3(160), dim3(512), 0, stream>>>(
        (const ushort*)obj_bf, (const ushort*)wbuf, cbias,
        wswo_bf, conv_bf, NTOT, D_);

    // 3. atten (bf16 ws/wo) + A build
    atten_kernel<<<dim3(RTOT), blk, 0, stream>>>(
        (const ushort*)wswo_bf, phr, rel, Ww_w, Ww_b, atten);
    build_A<<<dim3(NIMG), blk, 0, stream>>>(rel, atten, Anorm);

    // 4. P = conv_bf @ wt1r^T (1024 x 2048, K=2048) -> Pbuf
    gemm_p2<64, 64><<<dim3(512), blk, 0, stream>>>(
        (const ushort*)conv_bf, (const ushort*)wt1r, nullptr, nullptr,
        Pbuf, NTOT, DC, DC, 0);

    // 5. h = A*P1 + A^T*P2 + b, LN, relu -> bf16 (4 rows/block)
    amult_ln4<<<dim3(256), blk, 0, stream>>>(Anorm, Pbuf, Wt1_b, ln_g, ln_b, h_bf);

    // 6. out = relu(obj + h @ Wt2^T + b)
    gemm_p2<64, 128><<<dim3(512), blk, 0, stream>>>(
        (const ushort*)h_bf, (const ushort*)wt2b, Wt2_b, obj,
        out, NTOT, DT, D_, 2);
}